// Round 2
// baseline (1134.036 us; speedup 1.0000x reference)
//
#include <hip/hip_runtime.h>
#include <math.h>

#define NL 3
#define NB 32
#define NC 256
#define NC2 128
#define HZ 15
#define ZZ 225
#define XX 961
#define HMD 127

__device__ __forceinline__ float hat_int(float u){
  if (u <= -1.f) return 0.f;
  if (u <= 0.f){ float t = u + 1.f; return 0.5f*t*t; }
  if (u <= 1.f){ float t = 1.f - u; return 1.f - 0.5f*t*t; }
  return 1.f;
}

// ---------------- mask branch ----------------
__global__ __launch_bounds__(256) void k_mconv1(const float* __restrict__ mask,
    const float* __restrict__ w, const float* __restrict__ bias, float* __restrict__ out){
  int idx = blockIdx.x*256 + threadIdx.x;
  const int OH=125, OW=125;
  if (idx >= NB*4*OH*OW) return;
  int x = idx % OW, y = (idx/OW) % OH;
  int o = (idx/(OW*OH)) % 4, b = idx/(4*OW*OH);
  const float* mb = mask + (size_t)b*HMD*HMD;
  float acc = bias[o];
  #pragma unroll
  for (int ky=0;ky<3;ky++)
    #pragma unroll
    for (int kx=0;kx<3;kx++){
      float mv = mb[(y+ky)*HMD + (x+kx)];
      acc += w[((o*2+0)*3+ky)*3+kx]*mv;
      acc += w[((o*2+1)*3+ky)*3+kx]*(1.f-mv);
    }
  out[idx] = fmaxf(acc, 0.f);
}

__global__ __launch_bounds__(256) void k_mconv2(const float* __restrict__ in,
    const float* __restrict__ w, const float* __restrict__ bias, float* __restrict__ out){
  int idx = blockIdx.x*256 + threadIdx.x;
  const int OH=123, OW=123, IH=125, IW=125;
  if (idx >= NB*8*OH*OW) return;
  int x = idx % OW, y = (idx/OW) % OH;
  int o = (idx/(OW*OH)) % 8, b = idx/(8*OW*OH);
  float acc = bias[o];
  for (int ic=0; ic<4; ic++){
    const float* ib = in + (size_t)(b*4+ic)*IH*IW;
    #pragma unroll
    for (int ky=0;ky<3;ky++)
      #pragma unroll
      for (int kx=0;kx<3;kx++)
        acc += w[((o*4+ic)*3+ky)*3+kx]*ib[(y+ky)*IW + (x+kx)];
  }
  out[idx] = fmaxf(acc, 0.f);
}

__global__ __launch_bounds__(256) void k_resize(const float* __restrict__ in, float* __restrict__ out,
    int CH, int IH, int IW, int OH, int OW){
  int idx = blockIdx.x*256 + threadIdx.x;
  int total = NB*CH*OH*OW;
  if (idx >= total) return;
  int ox = idx % OW, oy = (idx/OW) % OH;
  int bc = idx/(OW*OH);
  float sy = (float)((double)(IH-1)/(double)(OH-1));
  float sx = (float)((double)(IW-1)/(double)(OW-1));
  float yf = (float)oy * sy, xfv = (float)ox * sx;
  int y0 = (int)floorf(yf); y0 = min(max(y0,0), IH-2);
  int x0 = (int)floorf(xfv); x0 = min(max(x0,0), IW-2);
  float wy = yf - (float)y0, wx = xfv - (float)x0;
  const float* p = in + (size_t)bc*IH*IW;
  float v00=p[y0*IW+x0], v01=p[y0*IW+x0+1], v10=p[(y0+1)*IW+x0], v11=p[(y0+1)*IW+x0+1];
  out[idx] = (v00*(1.f-wy)+v10*wy)*(1.f-wx) + (v01*(1.f-wy)+v11*wy)*wx;
}

__global__ __launch_bounds__(256) void k_conv3x3_same(const float* __restrict__ in,
    const float* __restrict__ w, const float* __restrict__ bias, float* __restrict__ out,
    int IC, int OC, int H, int W, int relu){
  int idx = blockIdx.x*256 + threadIdx.x;
  if (idx >= NB*OC*H*W) return;
  int x = idx % W, y = (idx/W) % H;
  int o = (idx/(W*H)) % OC, b = idx/(OC*W*H);
  float acc = bias[o];
  for (int ic=0; ic<IC; ic++){
    const float* ib = in + (size_t)(b*IC+ic)*H*W;
    for (int ky=-1;ky<=1;ky++){
      int yy = y+ky; if (yy<0||yy>=H) continue;
      for (int kx=-1;kx<=1;kx++){
        int xx = x+kx; if (xx<0||xx>=W) continue;
        acc += w[((o*IC+ic)*3+(ky+1))*3+(kx+1)]*ib[yy*W+xx];
      }
    }
  }
  out[idx] = relu ? fmaxf(acc,0.f) : acc;
}

// ---------------- generic projection GEMM: out[s][n] = sum_c A[c][s]*W[n][c] + b[n] ----------------
__global__ __launch_bounds__(256) void k_proj(const float* __restrict__ Abase,
    const float* __restrict__ Wbase, const float* __restrict__ bbase,
    float* __restrict__ Obase, int M, int N, int K, int ntn){
  int lb = blockIdx.y; int l = lb / NB;
  const float* A = Abase + (size_t)lb*K*M;
  const float* W = Wbase + (size_t)l*N*K;
  const float* bias = bbase + (size_t)l*N;
  float* out = Obase + (size_t)lb*M*N;
  int tm = blockIdx.x / ntn, tn = blockIdx.x % ntn;
  int s0 = tm*32, n0 = tn*32;
  __shared__ float As[32][33];  // [k_local][m_local]
  __shared__ float Ws[32][33];  // [n_local][k_local]
  int t = threadIdx.x;
  int ni = t & 31, mi = (t >> 5) * 4;
  float acc[4] = {0.f,0.f,0.f,0.f};
  for (int kc=0; kc<K; kc+=32){
    #pragma unroll
    for (int r=0;r<4;r++){
      int e = r*256 + t;
      int rr = e >> 5, cc = e & 31;
      As[rr][cc] = (s0+cc < M) ? A[(size_t)(kc+rr)*M + s0+cc] : 0.f;
      Ws[rr][cc] = W[(size_t)(n0+rr)*K + kc+cc];
    }
    __syncthreads();
    #pragma unroll
    for (int cc=0; cc<32; cc++){
      float wv = Ws[ni][cc];
      #pragma unroll
      for (int j=0;j<4;j++) acc[j] += As[cc][mi+j]*wv;
    }
    __syncthreads();
  }
  float bv = bias[n0+ni];
  #pragma unroll
  for (int j=0;j<4;j++){
    int s = s0+mi+j;
    if (s < M) out[(size_t)s*N + n0+ni] = acc[j] + bv;
  }
}

// ---------------- S = TH @ PHt^T ----------------
__global__ __launch_bounds__(256) void k_scores(const float* __restrict__ TH,
    const float* __restrict__ PHt, float* __restrict__ S){
  int lb = blockIdx.y;
  const float* A = TH + (size_t)lb*ZZ*NC2;
  const float* Bm = PHt + (size_t)lb*ZZ*NC2;
  float* out = S + (size_t)lb*ZZ*ZZ;
  int tm = blockIdx.x >> 3, tn = blockIdx.x & 7;
  int i0 = tm*32, j0 = tn*32;
  __shared__ float As[32][33];
  __shared__ float Bs[32][33];
  int t = threadIdx.x;
  int ji = t & 31, ii = (t>>5)*4;
  float acc[4] = {0,0,0,0};
  for (int kc=0; kc<NC2; kc+=32){
    #pragma unroll
    for (int r=0;r<4;r++){
      int e = r*256+t; int rr = e>>5, cc = e&31;
      As[rr][cc] = (i0+rr<ZZ) ? A[(size_t)(i0+rr)*NC2 + kc+cc] : 0.f;
      Bs[rr][cc] = (j0+rr<ZZ) ? Bm[(size_t)(j0+rr)*NC2 + kc+cc] : 0.f;
    }
    __syncthreads();
    #pragma unroll
    for (int cc=0; cc<32; cc++){
      float bv = Bs[ji][cc];
      #pragma unroll
      for (int j=0;j<4;j++) acc[j] += As[ii+j][cc]*bv;
    }
    __syncthreads();
  }
  #pragma unroll
  for (int j=0;j<4;j++){
    int i = i0+ii+j;
    if (i<ZZ && j0+ji<ZZ) out[(size_t)i*ZZ + j0+ji] = acc[j];
  }
}

// ---------------- softmax rows of S (in place), fold 1/sqrt(C) ----------------
__global__ __launch_bounds__(256) void k_softmax(float* __restrict__ S){
  int row = blockIdx.x*4 + (threadIdx.x >> 6);
  int lane = threadIdx.x & 63;
  float* r = S + (size_t)row*ZZ;
  float v[4]; float mx = -1e30f;
  #pragma unroll
  for (int q=0;q<4;q++){
    int j = lane + q*64;
    v[q] = (j<ZZ) ? r[j] : -1e30f;
    mx = fmaxf(mx, v[q]);
  }
  #pragma unroll
  for (int off=32; off>0; off>>=1) mx = fmaxf(mx, __shfl_xor(mx, off));
  float sum = 0.f;
  #pragma unroll
  for (int q=0;q<4;q++){
    v[q] = __expf(v[q]-mx);
    if (lane + q*64 < ZZ) sum += v[q];
  }
  #pragma unroll
  for (int off=32; off>0; off>>=1) sum += __shfl_xor(sum, off);
  float inv = 1.f/(16.f*sum);
  #pragma unroll
  for (int q=0;q<4;q++){
    int j = lane + q*64;
    if (j<ZZ) r[j] = v[q]*inv;
  }
}

// ---------------- Y = P @ GX ----------------
__global__ __launch_bounds__(256) void k_pv(const float* __restrict__ P,
    const float* __restrict__ GX, float* __restrict__ Y){
  int lb = blockIdx.y;
  const float* A = P + (size_t)lb*ZZ*ZZ;
  const float* Bm = GX + (size_t)lb*ZZ*NC2;
  float* out = Y + (size_t)lb*ZZ*NC2;
  int tm = blockIdx.x >> 2, tn = blockIdx.x & 3;
  int i0 = tm*32, k0 = tn*32;
  __shared__ float As[32][33];  // [i][j]
  __shared__ float Bs[32][33];  // [j][k]
  int t = threadIdx.x;
  int ki = t & 31, ii = (t>>5)*4;
  float acc[4] = {0,0,0,0};
  for (int jc=0; jc<ZZ; jc+=32){
    #pragma unroll
    for (int r=0;r<4;r++){
      int e = r*256+t; int rr = e>>5, cc = e&31;
      As[rr][cc] = (i0+rr<ZZ && jc+cc<ZZ) ? A[(size_t)(i0+rr)*ZZ + jc+cc] : 0.f;
      Bs[rr][cc] = (jc+rr<ZZ) ? Bm[(size_t)(jc+rr)*NC2 + k0+cc] : 0.f;
    }
    __syncthreads();
    #pragma unroll
    for (int jj=0; jj<32; jj++){
      float bv = Bs[jj][ki];
      #pragma unroll
      for (int q=0;q<4;q++) acc[q] += As[ii+q][jj]*bv;
    }
    __syncthreads();
  }
  #pragma unroll
  for (int q=0;q<4;q++){
    int i = i0+ii+q;
    if (i<ZZ) out[(size_t)i*NC2 + k0+ki] = acc[q];
  }
}

// ---------------- self_attn = BN(outw @ Y^T); zf_full = (1+cues)*zf + self_attn; + 7x7 slice ----------------
__global__ __launch_bounds__(256) void k_outconv(const float* __restrict__ Y,
    const float* __restrict__ outw, const float* __restrict__ bng, const float* __restrict__ bnb,
    const float* __restrict__ bnm, const float* __restrict__ bnv,
    const float* __restrict__ cues, const float* __restrict__ zf,
    float* __restrict__ dzfout, float* __restrict__ dzffull){
  int lb = blockIdx.y; int l = lb/NB;
  const float* A = outw + (size_t)l*NC*NC2;  // [c][k]
  const float* Bm = Y + (size_t)lb*ZZ*NC2;   // [z][k]
  int tm = blockIdx.x >> 3, tn = blockIdx.x & 7;
  int c0 = tm*32, z0 = tn*32;
  __shared__ float As[32][33];
  __shared__ float Bs[32][33];
  int t = threadIdx.x;
  int zi = t & 31, ci = (t>>5)*4;
  float acc[4] = {0,0,0,0};
  for (int kc=0; kc<NC2; kc+=32){
    #pragma unroll
    for (int r=0;r<4;r++){
      int e = r*256+t; int rr=e>>5, cc=e&31;
      As[rr][cc] = A[(size_t)(c0+rr)*NC2 + kc+cc];
      Bs[rr][cc] = (z0+rr<ZZ) ? Bm[(size_t)(z0+rr)*NC2 + kc+cc] : 0.f;
    }
    __syncthreads();
    #pragma unroll
    for (int cc=0; cc<32; cc++){
      float bv = Bs[zi][cc];
      #pragma unroll
      for (int q=0;q<4;q++) acc[q] += As[ci+q][cc]*bv;
    }
    __syncthreads();
  }
  int z = z0+zi;
  if (z < ZZ){
    int h = z/15, wv2 = z%15;
    #pragma unroll
    for (int q=0;q<4;q++){
      int c = c0+ci+q;
      float scale = bng[l*NC+c] * rsqrtf(bnv[l*NC+c] + 1e-5f);
      float val = (acc[q] - bnm[l*NC+c])*scale + bnb[l*NC+c];
      float cu = cues[(size_t)lb*NC + c];
      float zv = zf[((size_t)lb*NC + c)*ZZ + z];
      float rr = cu*zv + zv + val;
      dzffull[((size_t)lb*NC + c)*ZZ + z] = rr;
      if (h>=4 && h<11 && wv2>=4 && wv2<11)
        dzfout[((size_t)lb*NC + c)*49 + (h-4)*7 + (wv2-4)] = rr;
    }
  }
}

// ---------------- PrRoI pooling ----------------
__global__ __launch_bounds__(256) void k_rois(const float* __restrict__ zf,
    const float* __restrict__ box, float* __restrict__ rois){
  int lb = blockIdx.x; int b = lb % NB;
  __shared__ float Wy[7][15], Wx[7][15];
  __shared__ float tmp[64][7][16];
  __shared__ float area_s;
  int t = threadIdx.x;
  const float* bx = box + b*4;
  const float SC = 15.0f/127.0f;
  float x1 = bx[0]*SC, y1 = bx[1]*SC, x2 = bx[2]*SC, y2 = bx[3]*SC;
  float bh = (y2-y1)/7.f, bw = (x2-x1)/7.f;
  if (t < 105){ int p=t/15, i=t%15;
    Wy[p][i] = hat_int(y1+(float)(p+1)*bh - (float)i) - hat_int(y1+(float)p*bh - (float)i); }
  else if (t < 210){ int q=(t-105)/15, i=(t-105)%15;
    Wx[q][i] = hat_int(x1+(float)(q+1)*bw - (float)i) - hat_int(x1+(float)q*bw - (float)i); }
  if (t == 255) area_s = fmaxf(bh*bw, 1e-6f);
  __syncthreads();
  float inv_area = 1.f/area_s;
  const float* f = zf + (size_t)lb*NC*ZZ;
  float* out = rois + (size_t)lb*NC*49;
  for (int c0=0; c0<NC; c0+=64){
    for (int e=t; e<64*105; e+=256){
      int w = e%15, p = (e/15)%7, cc = e/105;
      float s = 0.f;
      #pragma unroll
      for (int h=0;h<15;h++) s += Wy[p][h]*f[(size_t)(c0+cc)*ZZ + h*15 + w];
      tmp[cc][p][w] = s;
    }
    __syncthreads();
    for (int e=t; e<64*49; e+=256){
      int q = e%7, p = (e/7)%7, cc = e/49;
      float s = 0.f;
      #pragma unroll
      for (int w=0;w<15;w++) s += tmp[cc][p][w]*Wx[q][w];
      out[(size_t)(c0+cc)*49 + p*7 + q] = s*inv_area;
    }
    __syncthreads();
  }
}

__global__ __launch_bounds__(256) void k_pool(const float* __restrict__ rois,
    float* __restrict__ pavg, float* __restrict__ pmax){
  int idx = blockIdx.x*256 + threadIdx.x;
  if (idx >= NL*NB*NC) return;
  const float* r = rois + (size_t)idx*49;
  float s = 0.f, m = -1e30f;
  #pragma unroll
  for (int i=0;i<49;i++){ float v = r[i]; s += v; m = fmaxf(m,v); }
  pavg[idx] = s/49.f;
  pmax[idx] = m;
}

__global__ __launch_bounds__(256) void k_mlp(const float* __restrict__ pavg, const float* __restrict__ pmax,
    const float* __restrict__ aw1, const float* __restrict__ ab1, const float* __restrict__ aw2, const float* __restrict__ ab2,
    const float* __restrict__ mw1, const float* __restrict__ mb1, const float* __restrict__ mw2, const float* __restrict__ mb2,
    float* __restrict__ zavg, float* __restrict__ zmax){
  int lb = blockIdx.x; int l = lb/NB;
  __shared__ float pin[NC];
  __shared__ float hid[NC2];
  int t = threadIdx.x;
  pin[t] = pavg[(size_t)lb*NC + t];
  __syncthreads();
  if (t < NC2){
    float a = ab1[l*NC2+t];
    const float* wr = aw1 + (size_t)(l*NC2+t)*NC;
    for (int c=0;c<NC;c++) a += wr[c]*pin[c];
    hid[t] = fmaxf(a, 0.f);
  }
  __syncthreads();
  {
    float a = ab2[l*NC+t];
    const float* wr = aw2 + (size_t)(l*NC+t)*NC2;
    for (int h=0;h<NC2;h++) a += wr[h]*hid[h];
    zavg[(size_t)lb*NC+t] = a;
  }
  __syncthreads();
  pin[t] = pmax[(size_t)lb*NC + t];
  __syncthreads();
  if (t < NC2){
    float a = mb1[l*NC2+t];
    const float* wr = mw1 + (size_t)(l*NC2+t)*NC;
    for (int c=0;c<NC;c++) a += wr[c]*pin[c];
    hid[t] = fmaxf(a, 0.f);
  }
  __syncthreads();
  {
    float a = mb2[l*NC+t];
    const float* wr = mw2 + (size_t)(l*NC+t)*NC2;
    for (int h=0;h<NC2;h++) a += wr[h]*hid[h];
    zmax[(size_t)lb*NC+t] = a;
  }
}

// ---------------- chan_z fused: f rows on the fly ----------------
__global__ __launch_bounds__(256) void k_z2n(const float* __restrict__ czth, const float* __restrict__ czph,
    const float* __restrict__ gw, const float* __restrict__ gb,
    const float* __restrict__ aw, const float* __restrict__ ab,
    float* __restrict__ z2n){
  int lb = blockIdx.x; int l = lb/NB;
  __shared__ float ph_s[NC][51];
  __shared__ float rel[2*NC];
  int t = threadIdx.x;
  const float* thp = czth + (size_t)lb*49*NC;
  const float* php = czph + (size_t)lb*49*NC;
  for (int e=t; e<49*NC; e+=256){
    int g = e & 255, s = e >> 8;
    ph_s[g][s] = php[(size_t)s*NC + g];
  }
  float tr[49];
  #pragma unroll
  for (int s=0;s<49;s++) tr[s] = thp[(size_t)s*NC + t];
  __syncthreads();
  const float* gwl = gw + (size_t)l*512*NC;
  float a0 = 0.f, a1 = 0.f;
  for (int h=0; h<NC; h++){
    float fv = 0.f;
    #pragma unroll
    for (int s=0;s<49;s++) fv += tr[s]*ph_s[h][s];
    a0 += gwl[(size_t)(t*2+0)*NC + h]*fv;
    a1 += gwl[(size_t)(t*2+1)*NC + h]*fv;
  }
  a0 = fmaxf(a0 + gb[l*512 + t*2+0], 0.f);
  a1 = fmaxf(a1 + gb[l*512 + t*2+1], 0.f);
  rel[t*2+0] = a0; rel[t*2+1] = a1;
  __syncthreads();
  float o = ab[l*NC + t];
  const float* awr = aw + (size_t)(l*NC+t)*512;
  for (int c=0;c<512;c++) o += awr[c]*rel[c];
  z2n[(size_t)lb*NC + t] = o;
}

__global__ __launch_bounds__(256) void k_cues(const float* __restrict__ zavg, const float* __restrict__ zmax,
    const float* __restrict__ z2n, const float* __restrict__ drw, const float* __restrict__ drb,
    float* __restrict__ cues){
  int idx = blockIdx.x*256 + threadIdx.x;
  if (idx >= NL*NB*NC) return;
  int c = idx & 255; int lb = idx >> 8; int l = lb/NB;
  const float* dw = drw + (size_t)(l*NC + c)*3;
  float x = dw[0]*zavg[idx] + dw[1]*zmax[idx] + dw[2]*z2n[idx] + drb[l*NC+c];
  cues[idx] = 1.f/(1.f + __expf(-x));
}

// ---------------- collapsed sc branch ----------------
__global__ __launch_bounds__(256) void k_zm(const float* __restrict__ zf, const float* __restrict__ m3,
    float* __restrict__ zm, float* __restrict__ sm){
  int lb = blockIdx.x;
  __shared__ float ms[ZZ];
  int t = threadIdx.x;
  if (t < ZZ) ms[t] = m3[(size_t)lb*ZZ + t];
  __syncthreads();
  const float* zr = zf + ((size_t)lb*NC + t)*ZZ;
  float s = 0.f;
  for (int z=0; z<ZZ; z++) s += zr[z]*ms[z];
  zm[(size_t)lb*NC + t] = s;
  if (t == 0){
    float ss = 0.f;
    for (int z=0; z<ZZ; z++) ss += ms[z];
    sm[lb] = ss;
  }
}

__global__ __launch_bounds__(256) void k_zphi(const float* __restrict__ zm, const float* __restrict__ sm,
    const float* __restrict__ phiw, const float* __restrict__ phib, float* __restrict__ zphi){
  int lb = blockIdx.x; int l = lb/NB;
  __shared__ float zms[NC];
  int t = threadIdx.x;
  zms[t] = zm[(size_t)lb*NC + t];
  __syncthreads();
  const float* wr = phiw + (size_t)(l*NC + t)*NC;
  float s = phib[l*NC + t]*sm[lb];
  for (int k=0;k<NC;k++) s += wr[k]*zms[k];
  zphi[(size_t)lb*NC + t] = s;
}

__global__ __launch_bounds__(256) void k_wvec(const float* __restrict__ zphi, const float* __restrict__ dw,
    const float* __restrict__ db, float* __restrict__ wvec, float* __restrict__ cb){
  int lb = blockIdx.x; int l = lb/NB;
  __shared__ float zp[NC];
  __shared__ float red[NC];
  int t = threadIdx.x;
  zp[t] = zphi[(size_t)lb*NC + t];
  __syncthreads();
  float s = 0.f;
  const float* dwl = dw + (size_t)l*NC*NC;
  for (int c=0;c<NC;c++) s += zp[c]*dwl[(size_t)c*NC + t];
  wvec[(size_t)lb*NC + t] = s;
  red[t] = zp[t]*db[l*NC + t];
  __syncthreads();
  for (int off2=128; off2>0; off2>>=1){
    if (t < off2) red[t] += red[t+off2];
    __syncthreads();
  }
  if (t==0) cb[lb] = red[0];
}

__global__ __launch_bounds__(256) void k_sc(const float* __restrict__ xf, const float* __restrict__ wvec,
    const float* __restrict__ cb, float* __restrict__ sc){
  int lb = blockIdx.x;
  __shared__ float wv[NC];
  int t = threadIdx.x;
  wv[t] = wvec[(size_t)lb*NC + t];
  __syncthreads();
  float cbv = cb[lb];
  const float* xb = xf + (size_t)lb*NC*XX;
  for (int x = t; x < XX; x += 256){
    float s = 0.f;
    for (int c=0;c<NC;c++) s += wv[c]*xb[(size_t)c*XX + x];
    float v = (s + cbv)*0.0625f;
    sc[(size_t)lb*XX + x] = fminf(fmaxf(v, 0.f), 1.f);
  }
}

__global__ __launch_bounds__(256) void k_xfout(const float* __restrict__ xf, const float* __restrict__ cues,
    const float* __restrict__ sc, float* __restrict__ out){
  int bc = blockIdx.y;
  int x = blockIdx.x*256 + threadIdx.x;
  if (x >= XX) return;
  int lb = bc >> 8;
  float cu = cues[bc];
  out[(size_t)bc*XX + x] = (1.f+cu)*xf[(size_t)bc*XX + x] - sc[(size_t)lb*XX + x];
}

extern "C" void kernel_launch(void* const* d_in, const int* in_sizes, int n_in,
                              void* d_out, int out_size, void* d_ws, size_t ws_size,
                              hipStream_t stream){
  const float* zf      = (const float*)d_in[0];
  const float* xf      = (const float*)d_in[1];
  const float* maskp   = (const float*)d_in[2];
  const float* box     = (const float*)d_in[3];
  const float* nl_g_w  = (const float*)d_in[4];
  const float* nl_g_b  = (const float*)d_in[5];
  const float* nl_th_w = (const float*)d_in[6];
  const float* nl_th_b = (const float*)d_in[7];
  const float* nl_ph_w = (const float*)d_in[8];
  const float* nl_ph_b = (const float*)d_in[9];
  const float* nl_out_w= (const float*)d_in[10];
  const float* bn_g    = (const float*)d_in[11];
  const float* bn_b    = (const float*)d_in[12];
  const float* bn_m    = (const float*)d_in[13];
  const float* bn_v    = (const float*)d_in[14];
  const float* cz_th_w = (const float*)d_in[15];
  const float* cz_th_b = (const float*)d_in[16];
  const float* cz_ph_w = (const float*)d_in[17];
  const float* cz_ph_b = (const float*)d_in[18];
  const float* cz_gw   = (const float*)d_in[19];
  const float* cz_gb   = (const float*)d_in[20];
  const float* cz_aw   = (const float*)d_in[21];
  const float* cz_ab   = (const float*)d_in[22];
  const float* ap_w1   = (const float*)d_in[23];
  const float* ap_b1   = (const float*)d_in[24];
  const float* ap_w2   = (const float*)d_in[25];
  const float* ap_b2   = (const float*)d_in[26];
  const float* mp_w1   = (const float*)d_in[27];
  const float* mp_b1   = (const float*)d_in[28];
  const float* mp_w2   = (const float*)d_in[29];
  const float* mp_b2   = (const float*)d_in[30];
  const float* dr_w    = (const float*)d_in[31];
  const float* dr_b    = (const float*)d_in[32];
  const float* ac1_w   = (const float*)d_in[33];
  const float* ac1_b   = (const float*)d_in[34];
  const float* ac2_w   = (const float*)d_in[35];
  const float* ac2_b   = (const float*)d_in[36];
  const float* ac3_w   = (const float*)d_in[37];
  const float* ac3_b   = (const float*)d_in[38];
  const float* ac4_w   = (const float*)d_in[39];
  const float* ac4_b   = (const float*)d_in[40];
  const float* phi_w   = (const float*)d_in[41];
  const float* phi_b   = (const float*)d_in[42];
  const float* delta_w = (const float*)d_in[43];
  const float* delta_b = (const float*)d_in[44];
  (void)in_sizes; (void)n_in; (void)out_size; (void)ws_size;

  float* ws = (float*)d_ws;
  size_t off = 0;
  auto alloc = [&](size_t n){ size_t o = off; off += (n + 15) & ~(size_t)15; return o; };

  float* c1   = ws + alloc((size_t)NB*4*125*125);
  float* c2   = ws + alloc((size_t)NB*8*123*123);
  float* r1   = ws + alloc((size_t)NB*8*14*14);
  float* c3   = ws + alloc((size_t)NB*4*14*14);
  float* r2   = ws + alloc((size_t)NB*4*15*15);
  float* m3   = ws + alloc((size_t)NL*NB*ZZ);
  float* TH   = ws + alloc((size_t)NL*NB*ZZ*NC2);
  float* PHt  = ws + alloc((size_t)NL*NB*ZZ*NC2);
  float* GX   = ws + alloc((size_t)NL*NB*ZZ*NC2);
  float* S    = ws + alloc((size_t)NL*NB*ZZ*ZZ);
  float* Yb   = ws + alloc((size_t)NL*NB*ZZ*NC2);
  float* rois = ws + alloc((size_t)NL*NB*NC*49);
  float* pavg = ws + alloc((size_t)NL*NB*NC);
  float* pmax = ws + alloc((size_t)NL*NB*NC);
  float* zavg = ws + alloc((size_t)NL*NB*NC);
  float* zmax = ws + alloc((size_t)NL*NB*NC);
  float* z2n  = ws + alloc((size_t)NL*NB*NC);
  float* cues = ws + alloc((size_t)NL*NB*NC);
  float* zm   = ws + alloc((size_t)NL*NB*NC);
  float* zphi = ws + alloc((size_t)NL*NB*NC);
  float* wvec = ws + alloc((size_t)NL*NB*NC);
  float* czth = ws + alloc((size_t)NL*NB*49*NC);
  float* czph = ws + alloc((size_t)NL*NB*49*NC);
  float* sm   = ws + alloc((size_t)NL*NB);
  float* cbuf = ws + alloc((size_t)NL*NB);
  float* scb  = ws + alloc((size_t)NL*NB*XX);

  float* outp    = (float*)d_out;
  float* o_zfout = outp;
  float* o_zffull= outp + (size_t)NL*NB*NC*49;
  float* o_xfout = o_zffull + (size_t)NL*NB*NC*ZZ;

  // ---- mask branch (per layer: weights differ) ----
  for (int l=0; l<NL; l++){
    k_mconv1<<<(NB*4*125*125+255)/256, 256, 0, stream>>>(maskp, ac1_w + (size_t)l*4*2*9, ac1_b + l*4, c1);
    k_mconv2<<<(NB*8*123*123+255)/256, 256, 0, stream>>>(c1, ac2_w + (size_t)l*8*4*9, ac2_b + l*8, c2);
    k_resize<<<(NB*8*14*14+255)/256, 256, 0, stream>>>(c2, r1, 8, 123, 123, 14, 14);
    k_conv3x3_same<<<(NB*4*14*14+255)/256, 256, 0, stream>>>(r1, ac3_w + (size_t)l*4*8*9, ac3_b + l*4, c3, 8, 4, 14, 14, 0);
    k_resize<<<(NB*4*15*15+255)/256, 256, 0, stream>>>(c3, r2, 4, 14, 14, 15, 15);
    k_conv3x3_same<<<(NB*1*15*15+255)/256, 256, 0, stream>>>(r2, ac4_w + (size_t)l*1*4*9, ac4_b + l*1, m3 + (size_t)l*NB*ZZ, 4, 1, 15, 15, 0);
  }

  // ---- non-local projections ----
  dim3 gproj(32, NL*NB);
  k_proj<<<gproj, 256, 0, stream>>>(zf, nl_th_w, nl_th_b, TH,  ZZ, NC2, NC, 4);
  k_proj<<<gproj, 256, 0, stream>>>(zf, nl_ph_w, nl_ph_b, PHt, ZZ, NC2, NC, 4);
  k_proj<<<gproj, 256, 0, stream>>>(zf, nl_g_w,  nl_g_b,  GX,  ZZ, NC2, NC, 4);
  k_scores<<<dim3(64, NL*NB), 256, 0, stream>>>(TH, PHt, S);
  k_softmax<<<(NL*NB*ZZ)/4, 256, 0, stream>>>(S);
  k_pv<<<dim3(32, NL*NB), 256, 0, stream>>>(S, GX, Yb);

  // ---- rois / cues ----
  k_rois<<<NL*NB, 256, 0, stream>>>(zf, box, rois);
  k_pool<<<(NL*NB*NC+255)/256, 256, 0, stream>>>(rois, pavg, pmax);
  k_mlp<<<NL*NB, 256, 0, stream>>>(pavg, pmax, ap_w1, ap_b1, ap_w2, ap_b2,
                                    mp_w1, mp_b1, mp_w2, mp_b2, zavg, zmax);
  k_proj<<<dim3(16, NL*NB), 256, 0, stream>>>(rois, cz_th_w, cz_th_b, czth, 49, NC, NC, 8);
  k_proj<<<dim3(16, NL*NB), 256, 0, stream>>>(rois, cz_ph_w, cz_ph_b, czph, 49, NC, NC, 8);
  k_z2n<<<NL*NB, 256, 0, stream>>>(czth, czph, cz_gw, cz_gb, cz_aw, cz_ab, z2n);
  k_cues<<<(NL*NB*NC+255)/256, 256, 0, stream>>>(zavg, zmax, z2n, dr_w, dr_b, cues);

  // ---- zf_full (+7x7 slice) ----
  k_outconv<<<dim3(64, NL*NB), 256, 0, stream>>>(Yb, nl_out_w, bn_g, bn_b, bn_m, bn_v,
                                                  cues, zf, o_zfout, o_zffull);

  // ---- collapsed sc branch + xf_out ----
  k_zm<<<NL*NB, 256, 0, stream>>>(zf, m3, zm, sm);
  k_zphi<<<NL*NB, 256, 0, stream>>>(zm, sm, phi_w, phi_b, zphi);
  k_wvec<<<NL*NB, 256, 0, stream>>>(zphi, delta_w, delta_b, wvec, cbuf);
  k_sc<<<NL*NB, 256, 0, stream>>>(xf, wvec, cbuf, scb);
  k_xfout<<<dim3(4, NL*NB*NC), 256, 0, stream>>>(xf, cues, scb, o_xfout);
}

// Round 4
// 897.476 us; speedup vs baseline: 1.2636x; 1.2636x over previous
//
#include <hip/hip_runtime.h>
#include <math.h>

#define NL 3
#define NB 32
#define NC 256
#define NC2 128
#define HZ 15
#define ZZ 225
#define XX 961
#define HMD 127

__device__ __forceinline__ float hat_int(float u){
  if (u <= -1.f) return 0.f;
  if (u <= 0.f){ float t = u + 1.f; return 0.5f*t*t; }
  if (u <= 1.f){ float t = 1.f - u; return 1.f - 0.5f*t*t; }
  return 1.f;
}

// ---------------- mask branch ----------------
__global__ __launch_bounds__(256) void k_mconv1(const float* __restrict__ mask,
    const float* __restrict__ w, const float* __restrict__ bias, float* __restrict__ out){
  int idx = blockIdx.x*256 + threadIdx.x;
  const int OH=125, OW=125;
  if (idx >= NB*4*OH*OW) return;
  int x = idx % OW, y = (idx/OW) % OH;
  int o = (idx/(OW*OH)) % 4, b = idx/(4*OW*OH);
  const float* mb = mask + (size_t)b*HMD*HMD;
  float acc = bias[o];
  #pragma unroll
  for (int ky=0;ky<3;ky++)
    #pragma unroll
    for (int kx=0;kx<3;kx++){
      float mv = mb[(y+ky)*HMD + (x+kx)];
      acc += w[((o*2+0)*3+ky)*3+kx]*mv;
      acc += w[((o*2+1)*3+ky)*3+kx]*(1.f-mv);
    }
  out[idx] = fmaxf(acc, 0.f);
}

__global__ __launch_bounds__(256) void k_mconv2(const float* __restrict__ in,
    const float* __restrict__ w, const float* __restrict__ bias, float* __restrict__ out){
  int idx = blockIdx.x*256 + threadIdx.x;
  const int OH=123, OW=123, IH=125, IW=125;
  if (idx >= NB*8*OH*OW) return;
  int x = idx % OW, y = (idx/OW) % OH;
  int o = (idx/(OW*OH)) % 8, b = idx/(8*OW*OH);
  float acc = bias[o];
  for (int ic=0; ic<4; ic++){
    const float* ib = in + (size_t)(b*4+ic)*IH*IW;
    #pragma unroll
    for (int ky=0;ky<3;ky++)
      #pragma unroll
      for (int kx=0;kx<3;kx++)
        acc += w[((o*4+ic)*3+ky)*3+kx]*ib[(y+ky)*IW + (x+kx)];
  }
  out[idx] = fmaxf(acc, 0.f);
}

__global__ __launch_bounds__(256) void k_resize(const float* __restrict__ in, float* __restrict__ out,
    int CH, int IH, int IW, int OH, int OW){
  int idx = blockIdx.x*256 + threadIdx.x;
  int total = NB*CH*OH*OW;
  if (idx >= total) return;
  int ox = idx % OW, oy = (idx/OW) % OH;
  int bc = idx/(OW*OH);
  float sy = (float)((double)(IH-1)/(double)(OH-1));
  float sx = (float)((double)(IW-1)/(double)(OW-1));
  float yf = (float)oy * sy, xfv = (float)ox * sx;
  int y0 = (int)floorf(yf); y0 = min(max(y0,0), IH-2);
  int x0 = (int)floorf(xfv); x0 = min(max(x0,0), IW-2);
  float wy = yf - (float)y0, wx = xfv - (float)x0;
  const float* p = in + (size_t)bc*IH*IW;
  float v00=p[y0*IW+x0], v01=p[y0*IW+x0+1], v10=p[(y0+1)*IW+x0], v11=p[(y0+1)*IW+x0+1];
  out[idx] = (v00*(1.f-wy)+v10*wy)*(1.f-wx) + (v01*(1.f-wy)+v11*wy)*wx;
}

__global__ __launch_bounds__(256) void k_conv3x3_same(const float* __restrict__ in,
    const float* __restrict__ w, const float* __restrict__ bias, float* __restrict__ out,
    int IC, int OC, int H, int W, int relu){
  int idx = blockIdx.x*256 + threadIdx.x;
  if (idx >= NB*OC*H*W) return;
  int x = idx % W, y = (idx/W) % H;
  int o = (idx/(W*H)) % OC, b = idx/(OC*W*H);
  float acc = bias[o];
  for (int ic=0; ic<IC; ic++){
    const float* ib = in + (size_t)(b*IC+ic)*H*W;
    for (int ky=-1;ky<=1;ky++){
      int yy = y+ky; if (yy<0||yy>=H) continue;
      for (int kx=-1;kx<=1;kx++){
        int xx = x+kx; if (xx<0||xx>=W) continue;
        acc += w[((o*IC+ic)*3+(ky+1))*3+(kx+1)]*ib[yy*W+xx];
      }
    }
  }
  out[idx] = relu ? fmaxf(acc,0.f) : acc;
}

// ---------------- 64x64-tile fp32 GEMM, 4x4 per thread ----------------
// AMODE 0: A is [K][M] (stride M). AMODE 1: A is [M][K] (stride K).
// BMODE 0: B is [N][K] (stride K). BMODE 1: B is [K][N] (stride N).
// out: [M][N] per lb. B selected per-l (BPERL) or per-lb.
template<int AMODE, int BMODE, bool BPERL, bool HASBIAS>
__global__ __launch_bounds__(256) void k_gemm64(
    const float* __restrict__ Abase, const float* __restrict__ Bbase,
    const float* __restrict__ biasbase, float* __restrict__ Obase,
    int M, int N, int K, int ntn)
{
  int lb = blockIdx.y; int l = lb / NB;
  const float* A = Abase + (size_t)lb*M*K;
  const float* B = Bbase + (BPERL ? (size_t)l : (size_t)lb)*N*K;
  float* out = Obase + (size_t)lb*M*N;
  int tm = blockIdx.x / ntn, tn = blockIdx.x % ntn;
  int m0 = tm*64, n0 = tn*64;
  __shared__ float As[32][68];
  __shared__ float Bs[32][68];
  int t = threadIdx.x;
  int tx = t & 15, ty = t >> 4;
  float acc[4][4] = {};
  for (int kc=0; kc<K; kc+=32){
    #pragma unroll
    for (int r=0;r<8;r++){
      int e = r*256 + t;
      int mm, kk;
      if (AMODE==0){ mm = e & 63; kk = e >> 6; }
      else { kk = e & 31; mm = e >> 5; }
      float va = 0.f;
      { int m = m0+mm, k = kc+kk;
        if (m < M && k < K)
          va = (AMODE==0) ? A[(size_t)k*M + m] : A[(size_t)m*K + k]; }
      As[kk][mm] = va;
      int nn, kk2;
      if (BMODE==0){ kk2 = e & 31; nn = e >> 5; }
      else { nn = e & 63; kk2 = e >> 6; }
      float vb = 0.f;
      { int n = n0+nn, k = kc+kk2;
        if (n < N && k < K)
          vb = (BMODE==0) ? B[(size_t)n*K + k] : B[(size_t)k*N + n]; }
      Bs[kk2][nn] = vb;
    }
    __syncthreads();
    #pragma unroll
    for (int kk=0; kk<32; kk++){
      float4 av = *(const float4*)&As[kk][ty*4];
      float4 bv = *(const float4*)&Bs[kk][tx*4];
      float aa[4] = {av.x, av.y, av.z, av.w};
      float bb[4] = {bv.x, bv.y, bv.z, bv.w};
      #pragma unroll
      for (int i=0;i<4;i++)
        #pragma unroll
        for (int j=0;j<4;j++)
          acc[i][j] += aa[i]*bb[j];
    }
    __syncthreads();
  }
  const float* bias = HASBIAS ? (biasbase + (size_t)l*N) : nullptr;
  #pragma unroll
  for (int i=0;i<4;i++){
    int m = m0 + ty*4 + i;
    if (m >= M) continue;
    #pragma unroll
    for (int j=0;j<4;j++){
      int n = n0 + tx*4 + j;
      if (n < N) out[(size_t)m*N + n] = acc[i][j] + (HASBIAS ? bias[n] : 0.f);
    }
  }
}

// ---------------- softmax rows of S (in place), fold 1/sqrt(C) ----------------
__global__ __launch_bounds__(256) void k_softmax(float* __restrict__ S){
  int row = blockIdx.x*4 + (threadIdx.x >> 6);
  int lane = threadIdx.x & 63;
  float* r = S + (size_t)row*ZZ;
  float v[4]; float mx = -1e30f;
  #pragma unroll
  for (int q=0;q<4;q++){
    int j = lane + q*64;
    v[q] = (j<ZZ) ? r[j] : -1e30f;
    mx = fmaxf(mx, v[q]);
  }
  #pragma unroll
  for (int off=32; off>0; off>>=1) mx = fmaxf(mx, __shfl_xor(mx, off));
  float sum = 0.f;
  #pragma unroll
  for (int q=0;q<4;q++){
    v[q] = __expf(v[q]-mx);
    if (lane + q*64 < ZZ) sum += v[q];
  }
  #pragma unroll
  for (int off=32; off>0; off>>=1) sum += __shfl_xor(sum, off);
  float inv = 1.f/(16.f*sum);
  #pragma unroll
  for (int q=0;q<4;q++){
    int j = lane + q*64;
    if (j<ZZ) r[j] = v[q]*inv;
  }
}

// ---------------- outconv: 64x64 GEMM + BN/cues/residual epilogue ----------------
__global__ __launch_bounds__(256) void k_outconv(const float* __restrict__ Y,
    const float* __restrict__ outw, const float* __restrict__ bng, const float* __restrict__ bnb,
    const float* __restrict__ bnm, const float* __restrict__ bnv,
    const float* __restrict__ cues, const float* __restrict__ zf,
    float* __restrict__ dzfout, float* __restrict__ dzffull){
  int lb = blockIdx.y; int l = lb/NB;
  const float* A = outw + (size_t)l*NC*NC2;  // [c][k] stride NC2
  const float* B = Y + (size_t)lb*ZZ*NC2;    // [z][k] stride NC2
  int tm = blockIdx.x >> 2, tn = blockIdx.x & 3;
  int m0 = tm*64, n0 = tn*64;
  __shared__ float As[32][68];
  __shared__ float Bs[32][68];
  int t = threadIdx.x;
  int tx = t & 15, ty = t >> 4;
  float acc[4][4] = {};
  for (int kc=0; kc<NC2; kc+=32){
    #pragma unroll
    for (int r=0;r<8;r++){
      int e = r*256 + t;
      int kk = e & 31, mm = e >> 5;
      As[kk][mm] = A[(size_t)(m0+mm)*NC2 + kc+kk];
      float vb = 0.f;
      int n = n0+mm;
      if (n < ZZ) vb = B[(size_t)n*NC2 + kc+kk];
      Bs[kk][mm] = vb;
    }
    __syncthreads();
    #pragma unroll
    for (int kk=0; kk<32; kk++){
      float4 av = *(const float4*)&As[kk][ty*4];
      float4 bv = *(const float4*)&Bs[kk][tx*4];
      float aa[4] = {av.x, av.y, av.z, av.w};
      float bb[4] = {bv.x, bv.y, bv.z, bv.w};
      #pragma unroll
      for (int i=0;i<4;i++)
        #pragma unroll
        for (int j=0;j<4;j++)
          acc[i][j] += aa[i]*bb[j];
    }
    __syncthreads();
  }
  #pragma unroll
  for (int i=0;i<4;i++){
    int c = m0 + ty*4 + i;
    float scale = bng[l*NC+c] * rsqrtf(bnv[l*NC+c] + 1e-5f);
    float bm = bnm[l*NC+c], bb2 = bnb[l*NC+c];
    float cu = cues[(size_t)lb*NC + c];
    #pragma unroll
    for (int j=0;j<4;j++){
      int z = n0 + tx*4 + j;
      if (z >= ZZ) continue;
      float val = (acc[i][j] - bm)*scale + bb2;
      float zv = zf[((size_t)lb*NC + c)*ZZ + z];
      float rr = cu*zv + zv + val;
      dzffull[((size_t)lb*NC + c)*ZZ + z] = rr;
      int h = z/15, wv2 = z%15;
      if (h>=4 && h<11 && wv2>=4 && wv2<11)
        dzfout[((size_t)lb*NC + c)*49 + (h-4)*7 + (wv2-4)] = rr;
    }
  }
}

// ---------------- PrRoI pooling: block = (lb, 16-channel group) ----------------
__global__ __launch_bounds__(256) void k_rois(const float* __restrict__ zf,
    const float* __restrict__ box, float* __restrict__ rois){
  int lb = blockIdx.x; int b = lb % NB; int c0 = blockIdx.y*16;
  __shared__ float Wy[7][15], Wx[7][15];
  __shared__ float fld[16*ZZ];
  __shared__ float tmp[16][7][16];
  __shared__ float area_s;
  int t = threadIdx.x;
  const float* bx = box + b*4;
  const float SC = 15.0f/127.0f;
  float x1 = bx[0]*SC, y1 = bx[1]*SC, x2 = bx[2]*SC, y2 = bx[3]*SC;
  float bh = (y2-y1)/7.f, bw = (x2-x1)/7.f;
  if (t < 105){ int p=t/15, i=t%15;
    Wy[p][i] = hat_int(y1+(float)(p+1)*bh - (float)i) - hat_int(y1+(float)p*bh - (float)i); }
  else if (t < 210){ int q=(t-105)/15, i=(t-105)%15;
    Wx[q][i] = hat_int(x1+(float)(q+1)*bw - (float)i) - hat_int(x1+(float)q*bw - (float)i); }
  if (t == 255) area_s = fmaxf(bh*bw, 1e-6f);
  const float* src = zf + ((size_t)lb*NC + c0)*ZZ;
  for (int e=t; e<16*ZZ; e+=256) fld[e] = src[e];
  __syncthreads();
  float inv_area = 1.f/area_s;
  for (int e=t; e<16*105; e+=256){
    int w = e%15; int pc = e/15; int p = pc%7; int cc = pc/7;
    float s = 0.f;
    #pragma unroll
    for (int h=0;h<15;h++) s += Wy[p][h]*fld[cc*ZZ + h*15 + w];
    tmp[cc][p][w] = s;
  }
  __syncthreads();
  float* out = rois + ((size_t)lb*NC + c0)*49;
  for (int e=t; e<16*49; e+=256){
    int q = e%7; int pc = e/7; int p = pc%7; int cc = pc/7;
    float s = 0.f;
    #pragma unroll
    for (int w=0;w<15;w++) s += tmp[cc][p][w]*Wx[q][w];
    out[(size_t)cc*49 + p*7 + q] = s*inv_area;
  }
}

__global__ __launch_bounds__(256) void k_pool(const float* __restrict__ rois,
    float* __restrict__ pavg, float* __restrict__ pmax){
  int idx = blockIdx.x*256 + threadIdx.x;
  if (idx >= NL*NB*NC) return;
  const float* r = rois + (size_t)idx*49;
  float s = 0.f, m = -1e30f;
  #pragma unroll
  for (int i=0;i<49;i++){ float v = r[i]; s += v; m = fmaxf(m,v); }
  pavg[idx] = s/49.f;
  pmax[idx] = m;
}

__global__ __launch_bounds__(256) void k_mlp(const float* __restrict__ pavg, const float* __restrict__ pmax,
    const float* __restrict__ aw1, const float* __restrict__ ab1, const float* __restrict__ aw2, const float* __restrict__ ab2,
    const float* __restrict__ mw1, const float* __restrict__ mb1, const float* __restrict__ mw2, const float* __restrict__ mb2,
    float* __restrict__ zavg, float* __restrict__ zmax){
  int lb = blockIdx.x; int l = lb/NB;
  __shared__ float pin[NC];
  __shared__ float hid[NC2];
  int t = threadIdx.x;
  pin[t] = pavg[(size_t)lb*NC + t];
  __syncthreads();
  if (t < NC2){
    float a = ab1[l*NC2+t];
    const float* wr = aw1 + (size_t)(l*NC2+t)*NC;
    for (int c=0;c<NC;c++) a += wr[c]*pin[c];
    hid[t] = fmaxf(a, 0.f);
  }
  __syncthreads();
  {
    float a = ab2[l*NC+t];
    const float* wr = aw2 + (size_t)(l*NC+t)*NC2;
    for (int h=0;h<NC2;h++) a += wr[h]*hid[h];
    zavg[(size_t)lb*NC+t] = a;
  }
  __syncthreads();
  pin[t] = pmax[(size_t)lb*NC + t];
  __syncthreads();
  if (t < NC2){
    float a = mb1[l*NC2+t];
    const float* wr = mw1 + (size_t)(l*NC2+t)*NC;
    for (int c=0;c<NC;c++) a += wr[c]*pin[c];
    hid[t] = fmaxf(a, 0.f);
  }
  __syncthreads();
  {
    float a = mb2[l*NC+t];
    const float* wr = mw2 + (size_t)(l*NC+t)*NC2;
    for (int h=0;h<NC2;h++) a += wr[h]*hid[h];
    zmax[(size_t)lb*NC+t] = a;
  }
}

// ---------------- chan_z fused ----------------
__global__ __launch_bounds__(256) void k_z2n(const float* __restrict__ czth, const float* __restrict__ czph,
    const float* __restrict__ gw, const float* __restrict__ gb,
    const float* __restrict__ aw, const float* __restrict__ ab,
    float* __restrict__ z2n){
  int lb = blockIdx.x; int l = lb/NB;
  __shared__ float ph_s[NC][51];
  __shared__ float rel[2*NC];
  int t = threadIdx.x;
  const float* thp = czth + (size_t)lb*49*NC;
  const float* php = czph + (size_t)lb*49*NC;
  for (int e=t; e<49*NC; e+=256){
    int g = e & 255, s = e >> 8;
    ph_s[g][s] = php[(size_t)s*NC + g];
  }
  float tr[49];
  #pragma unroll
  for (int s=0;s<49;s++) tr[s] = thp[(size_t)s*NC + t];
  __syncthreads();
  const float* gwl = gw + (size_t)l*512*NC;
  float a0 = 0.f, a1 = 0.f;
  for (int h=0; h<NC; h++){
    float fv = 0.f;
    #pragma unroll
    for (int s=0;s<49;s++) fv += tr[s]*ph_s[h][s];
    a0 += gwl[(size_t)(t*2+0)*NC + h]*fv;
    a1 += gwl[(size_t)(t*2+1)*NC + h]*fv;
  }
  a0 = fmaxf(a0 + gb[l*512 + t*2+0], 0.f);
  a1 = fmaxf(a1 + gb[l*512 + t*2+1], 0.f);
  rel[t*2+0] = a0; rel[t*2+1] = a1;
  __syncthreads();
  float o = ab[l*NC + t];
  const float* awr = aw + (size_t)(l*NC+t)*512;
  for (int c=0;c<512;c++) o += awr[c]*rel[c];
  z2n[(size_t)lb*NC + t] = o;
}

__global__ __launch_bounds__(256) void k_cues(const float* __restrict__ zavg, const float* __restrict__ zmax,
    const float* __restrict__ z2n, const float* __restrict__ drw, const float* __restrict__ drb,
    float* __restrict__ cues){
  int idx = blockIdx.x*256 + threadIdx.x;
  if (idx >= NL*NB*NC) return;
  int c = idx & 255; int lb = idx >> 8; int l = lb/NB;
  const float* dw = drw + (size_t)(l*NC + c)*3;
  float x = dw[0]*zavg[idx] + dw[1]*zmax[idx] + dw[2]*z2n[idx] + drb[l*NC+c];
  cues[idx] = 1.f/(1.f + __expf(-x));
}

// ---------------- collapsed sc branch ----------------
__global__ __launch_bounds__(256) void k_zm(const float* __restrict__ zf, const float* __restrict__ m3,
    float* __restrict__ zm, float* __restrict__ sm){
  int lb = blockIdx.x; int cg = blockIdx.y;
  __shared__ float ms[ZZ];
  int t = threadIdx.x;
  if (t < ZZ) ms[t] = m3[(size_t)lb*ZZ + t];
  __syncthreads();
  int c = cg*32 + (t >> 3);
  int sub = t & 7;
  const float* zr = zf + ((size_t)lb*NC + c)*ZZ;
  float s = 0.f;
  for (int z=sub; z<ZZ; z+=8) s += zr[z]*ms[z];
  s += __shfl_down(s, 4, 8);
  s += __shfl_down(s, 2, 8);
  s += __shfl_down(s, 1, 8);
  if (sub == 0) zm[(size_t)lb*NC + c] = s;
  if (cg == 0 && t < 64){
    float ss = 0.f;
    for (int z=t; z<ZZ; z+=64) ss += ms[z];
    #pragma unroll
    for (int off=32; off>0; off>>=1) ss += __shfl_xor(ss, off);
    if (t == 0) sm[lb] = ss;
  }
}

__global__ __launch_bounds__(256) void k_zphi(const float* __restrict__ zm, const float* __restrict__ sm,
    const float* __restrict__ phiw, const float* __restrict__ phib, float* __restrict__ zphi){
  int lb = blockIdx.x; int l = lb/NB;
  __shared__ float zms[NC];
  int t = threadIdx.x;
  zms[t] = zm[(size_t)lb*NC + t];
  __syncthreads();
  const float* wr = phiw + (size_t)(l*NC + t)*NC;
  float s = phib[l*NC + t]*sm[lb];
  for (int k=0;k<NC;k++) s += wr[k]*zms[k];
  zphi[(size_t)lb*NC + t] = s;
}

__global__ __launch_bounds__(256) void k_wvec(const float* __restrict__ zphi, const float* __restrict__ dw,
    const float* __restrict__ db, float* __restrict__ wvec, float* __restrict__ cb){
  int lb = blockIdx.x; int l = lb/NB;
  __shared__ float zp[NC];
  __shared__ float red[NC];
  int t = threadIdx.x;
  zp[t] = zphi[(size_t)lb*NC + t];
  __syncthreads();
  float s = 0.f;
  const float* dwl = dw + (size_t)l*NC*NC;
  for (int c=0;c<NC;c++) s += zp[c]*dwl[(size_t)c*NC + t];
  wvec[(size_t)lb*NC + t] = s;
  red[t] = zp[t]*db[l*NC + t];
  __syncthreads();
  for (int off2=128; off2>0; off2>>=1){
    if (t < off2) red[t] += red[t+off2];
    __syncthreads();
  }
  if (t==0) cb[lb] = red[0];
}

__global__ __launch_bounds__(256) void k_sc(const float* __restrict__ xf, const float* __restrict__ wvec,
    const float* __restrict__ cb, float* __restrict__ sc){
  int lb = blockIdx.x;
  __shared__ float wv[NC];
  int t = threadIdx.x;
  wv[t] = wvec[(size_t)lb*NC + t];
  __syncthreads();
  float cbv = cb[lb];
  int x = blockIdx.y*256 + t;
  if (x >= XX) return;
  const float* xb = xf + (size_t)lb*NC*XX;
  float s = 0.f;
  for (int c=0;c<NC;c++) s += wv[c]*xb[(size_t)c*XX + x];
  float v = (s + cbv)*0.0625f;
  sc[(size_t)lb*XX + x] = fminf(fmaxf(v, 0.f), 1.f);
}

__global__ __launch_bounds__(256) void k_xfout(const float* __restrict__ xf, const float* __restrict__ cues,
    const float* __restrict__ sc, float* __restrict__ out){
  int bc = blockIdx.y;
  int x = blockIdx.x*256 + threadIdx.x;
  if (x >= XX) return;
  int lb = bc >> 8;
  float cu = cues[bc];
  out[(size_t)bc*XX + x] = (1.f+cu)*xf[(size_t)bc*XX + x] - sc[(size_t)lb*XX + x];
}

extern "C" void kernel_launch(void* const* d_in, const int* in_sizes, int n_in,
                              void* d_out, int out_size, void* d_ws, size_t ws_size,
                              hipStream_t stream){
  const float* zf      = (const float*)d_in[0];
  const float* xf      = (const float*)d_in[1];
  const float* maskp   = (const float*)d_in[2];
  const float* box     = (const float*)d_in[3];
  const float* nl_g_w  = (const float*)d_in[4];
  const float* nl_g_b  = (const float*)d_in[5];
  const float* nl_th_w = (const float*)d_in[6];
  const float* nl_th_b = (const float*)d_in[7];
  const float* nl_ph_w = (const float*)d_in[8];
  const float* nl_ph_b = (const float*)d_in[9];
  const float* nl_out_w= (const float*)d_in[10];
  const float* bn_g    = (const float*)d_in[11];
  const float* bn_b    = (const float*)d_in[12];
  const float* bn_m    = (const float*)d_in[13];
  const float* bn_v    = (const float*)d_in[14];
  const float* cz_th_w = (const float*)d_in[15];
  const float* cz_th_b = (const float*)d_in[16];
  const float* cz_ph_w = (const float*)d_in[17];
  const float* cz_ph_b = (const float*)d_in[18];
  const float* cz_gw   = (const float*)d_in[19];
  const float* cz_gb   = (const float*)d_in[20];
  const float* cz_aw   = (const float*)d_in[21];
  const float* cz_ab   = (const float*)d_in[22];
  const float* ap_w1   = (const float*)d_in[23];
  const float* ap_b1   = (const float*)d_in[24];
  const float* ap_w2   = (const float*)d_in[25];
  const float* ap_b2   = (const float*)d_in[26];
  const float* mp_w1   = (const float*)d_in[27];
  const float* mp_b1   = (const float*)d_in[28];
  const float* mp_w2   = (const float*)d_in[29];
  const float* mp_b2   = (const float*)d_in[30];
  const float* dr_w    = (const float*)d_in[31];
  const float* dr_b    = (const float*)d_in[32];
  const float* ac1_w   = (const float*)d_in[33];
  const float* ac1_b   = (const float*)d_in[34];
  const float* ac2_w   = (const float*)d_in[35];
  const float* ac2_b   = (const float*)d_in[36];
  const float* ac3_w   = (const float*)d_in[37];
  const float* ac3_b   = (const float*)d_in[38];
  const float* ac4_w   = (const float*)d_in[39];
  const float* ac4_b   = (const float*)d_in[40];
  const float* phi_w   = (const float*)d_in[41];
  const float* phi_b   = (const float*)d_in[42];
  const float* delta_w = (const float*)d_in[43];
  const float* delta_b = (const float*)d_in[44];
  (void)in_sizes; (void)n_in; (void)out_size; (void)ws_size;

  float* ws = (float*)d_ws;
  size_t off = 0;
  auto alloc = [&](size_t n){ size_t o = off; off += (n + 15) & ~(size_t)15; return o; };

  float* c1   = ws + alloc((size_t)NB*4*125*125);
  float* c2   = ws + alloc((size_t)NB*8*123*123);
  float* r1   = ws + alloc((size_t)NB*8*14*14);
  float* c3   = ws + alloc((size_t)NB*4*14*14);
  float* r2   = ws + alloc((size_t)NB*4*15*15);
  float* m3   = ws + alloc((size_t)NL*NB*ZZ);
  float* TH   = ws + alloc((size_t)NL*NB*ZZ*NC2);
  float* PHt  = ws + alloc((size_t)NL*NB*ZZ*NC2);
  float* GX   = ws + alloc((size_t)NL*NB*ZZ*NC2);
  float* S    = ws + alloc((size_t)NL*NB*ZZ*ZZ);
  float* Yb   = ws + alloc((size_t)NL*NB*ZZ*NC2);
  float* rois = ws + alloc((size_t)NL*NB*NC*49);
  float* pavg = ws + alloc((size_t)NL*NB*NC);
  float* pmax = ws + alloc((size_t)NL*NB*NC);
  float* zavg = ws + alloc((size_t)NL*NB*NC);
  float* zmax = ws + alloc((size_t)NL*NB*NC);
  float* z2n  = ws + alloc((size_t)NL*NB*NC);
  float* cues = ws + alloc((size_t)NL*NB*NC);
  float* zm   = ws + alloc((size_t)NL*NB*NC);
  float* zphi = ws + alloc((size_t)NL*NB*NC);
  float* wvec = ws + alloc((size_t)NL*NB*NC);
  float* czth = ws + alloc((size_t)NL*NB*49*NC);
  float* czph = ws + alloc((size_t)NL*NB*49*NC);
  float* sm   = ws + alloc((size_t)NL*NB);
  float* cbuf = ws + alloc((size_t)NL*NB);
  float* scb  = ws + alloc((size_t)NL*NB*XX);

  float* outp    = (float*)d_out;
  float* o_zfout = outp;
  float* o_zffull= outp + (size_t)NL*NB*NC*49;
  float* o_xfout = o_zffull + (size_t)NL*NB*NC*ZZ;

  // ---- mask branch ----
  for (int l=0; l<NL; l++){
    k_mconv1<<<(NB*4*125*125+255)/256, 256, 0, stream>>>(maskp, ac1_w + (size_t)l*4*2*9, ac1_b + l*4, c1);
    k_mconv2<<<(NB*8*123*123+255)/256, 256, 0, stream>>>(c1, ac2_w + (size_t)l*8*4*9, ac2_b + l*8, c2);
    k_resize<<<(NB*8*14*14+255)/256, 256, 0, stream>>>(c2, r1, 8, 123, 123, 14, 14);
    k_conv3x3_same<<<(NB*4*14*14+255)/256, 256, 0, stream>>>(r1, ac3_w + (size_t)l*4*8*9, ac3_b + l*4, c3, 8, 4, 14, 14, 0);
    k_resize<<<(NB*4*15*15+255)/256, 256, 0, stream>>>(c3, r2, 4, 14, 14, 15, 15);
    k_conv3x3_same<<<(NB*1*15*15+255)/256, 256, 0, stream>>>(r2, ac4_w + (size_t)l*1*4*9, ac4_b + l*1, m3 + (size_t)l*NB*ZZ, 4, 1, 15, 15, 0);
  }

  // ---- non-local projections (A = zf [K=256][M=225], W per-l [N][K]) ----
  dim3 gLB(8, NL*NB);
  k_gemm64<0,0,true,true><<<gLB, 256, 0, stream>>>(zf, nl_th_w, nl_th_b, TH,  ZZ, NC2, NC, 2);
  k_gemm64<0,0,true,true><<<gLB, 256, 0, stream>>>(zf, nl_ph_w, nl_ph_b, PHt, ZZ, NC2, NC, 2);
  k_gemm64<0,0,true,true><<<gLB, 256, 0, stream>>>(zf, nl_g_w,  nl_g_b,  GX,  ZZ, NC2, NC, 2);
  // S = TH[225][128] @ PHt[225][128]^T
  k_gemm64<1,0,false,false><<<dim3(16, NL*NB), 256, 0, stream>>>(TH, PHt, nullptr, S, ZZ, ZZ, NC2, 4);
  k_softmax<<<(NL*NB*ZZ)/4, 256, 0, stream>>>(S);
  // Y = P[225][225] @ GX[225][128]
  k_gemm64<1,1,false,false><<<dim3(8, NL*NB), 256, 0, stream>>>(S, GX, nullptr, Yb, ZZ, NC2, ZZ, 2);

  // ---- rois / cues ----
  k_rois<<<dim3(NL*NB, 16), 256, 0, stream>>>(zf, box, rois);
  k_pool<<<(NL*NB*NC+255)/256, 256, 0, stream>>>(rois, pavg, pmax);
  k_mlp<<<NL*NB, 256, 0, stream>>>(pavg, pmax, ap_w1, ap_b1, ap_w2, ap_b2,
                                    mp_w1, mp_b1, mp_w2, mp_b2, zavg, zmax);
  k_gemm64<0,0,true,true><<<dim3(4, NL*NB), 256, 0, stream>>>(rois, cz_th_w, cz_th_b, czth, 49, NC, NC, 4);
  k_gemm64<0,0,true,true><<<dim3(4, NL*NB), 256, 0, stream>>>(rois, cz_ph_w, cz_ph_b, czph, 49, NC, NC, 4);
  k_z2n<<<NL*NB, 256, 0, stream>>>(czth, czph, cz_gw, cz_gb, cz_aw, cz_ab, z2n);
  k_cues<<<(NL*NB*NC+255)/256, 256, 0, stream>>>(zavg, zmax, z2n, dr_w, dr_b, cues);

  // ---- zf_full (+7x7 slice) ----
  k_outconv<<<dim3(16, NL*NB), 256, 0, stream>>>(Yb, nl_out_w, bn_g, bn_b, bn_m, bn_v,
                                                  cues, zf, o_zfout, o_zffull);

  // ---- collapsed sc branch + xf_out ----
  k_zm<<<dim3(NL*NB, 8), 256, 0, stream>>>(zf, m3, zm, sm);
  k_zphi<<<NL*NB, 256, 0, stream>>>(zm, sm, phi_w, phi_b, zphi);
  k_wvec<<<NL*NB, 256, 0, stream>>>(zphi, delta_w, delta_b, wvec, cbuf);
  k_sc<<<dim3(NL*NB, 4), 256, 0, stream>>>(xf, wvec, cbuf, scb);
  k_xfout<<<dim3(4, NL*NB*NC), 256, 0, stream>>>(xf, cues, scb, o_xfout);
}